// Round 1
// baseline (258.706 us; speedup 1.0000x reference)
//
#include <hip/hip_runtime.h>

#define N_NODESC 50000
#define N_EDGESC 800000
#define MAXDEG 64

// ---------------- K0: zero-init deg + z (ws is poisoned 0xAA every call) ----
__global__ void k0_init(int* __restrict__ deg, float* __restrict__ z) {
    int i = blockIdx.x * 256 + threadIdx.x;
    if (i < N_NODESC) deg[i] = 0;
    if (i < 256) z[i] = 0.0f;
}

// ---------------- K1: padded-bucket CSR build (int atomics only) ------------
__global__ void k1_bucket(const int* __restrict__ ei, int* __restrict__ deg,
                          int* __restrict__ bucket) {
    int e = blockIdx.x * 256 + threadIdx.x;
    int src = ei[e];
    int dst = ei[N_EDGESC + e];
    int slot = atomicAdd(&deg[dst], 1);
    if (slot < MAXDEG) bucket[dst * MAXDEG + slot] = src;
}

// ---------------- K2: layer-1 mean aggregation. 1 wave/node, lane=channel ---
__global__ void k2_agg(const float* __restrict__ x, const int* __restrict__ deg,
                       const int* __restrict__ bucket, float* __restrict__ agg) {
    int lane = threadIdx.x & 63;
    int node = blockIdx.x * 4 + (threadIdx.x >> 6);
    int d = deg[node];
    int c = min(d, MAXDEG);
    const int* brow = bucket + node * MAXDEG;
    float a0 = 0.f, a1 = 0.f, a2 = 0.f, a3 = 0.f;
    int k = 0;
    // 4 independent gathers in flight per iteration (hide ~400cyc L2 latency)
    for (; k + 3 < c; k += 4) {
        int b0 = brow[k], b1 = brow[k + 1], b2 = brow[k + 2], b3 = brow[k + 3];
        a0 += x[b0 * 64 + lane];
        a1 += x[b1 * 64 + lane];
        a2 += x[b2 * 64 + lane];
        a3 += x[b3 * 64 + lane];
    }
    for (; k < c; ++k) a0 += x[brow[k] * 64 + lane];
    float inv = 1.0f / (float)max(d, 1);
    agg[node * 64 + lane] = (a0 + a1 + a2 + a3) * inv;
}

// ---------------- K3: fused layer-1 matmul + bias + relu + (s,t) dots -------
// Tile: 64 nodes x 128 outs. Thread (tx,ty): outs [tx*8,tx*8+8), nodes
// {ty, ty+16, ty+32, ty+48}. Two k-phases: ph0 = x@W1r.T, ph1 = agg@W1l.T.
// Epilogue: h1 = relu(acc + b1l); s = h1.w2l, t = h1.w2r reduced via LDS
// atomics -> h1 (25.6 MB) never hits HBM.
#define SWS 132   // weight tile stride [64 k][128 o]: (4k+o)%32 banks, 16B-aligned rows
#define XAS 68    // input tile stride  [64 n][64 k]

__launch_bounds__(256, 3)
__global__ void k3_mm_fused(const float* __restrict__ x, const float* __restrict__ agg,
                            const float* __restrict__ W1l, const float* __restrict__ b1l,
                            const float* __restrict__ W1r,
                            const float* __restrict__ W2l, const float* __restrict__ W2r,
                            float* __restrict__ s_out, float* __restrict__ t_out) {
    __shared__ __align__(16) float sW[64 * SWS];   // 33792 B
    __shared__ float sXA[64 * XAS];                // 17408 B
    __shared__ float sB[128], sL[128], sR[128];
    __shared__ float sS[64], sT[64];

    int tid = threadIdx.x;
    int node0 = blockIdx.x * 64;
    int tx = tid & 15;
    int ty = tid >> 4;

    if (tid < 128) { sB[tid] = b1l[tid]; sL[tid] = W2l[tid]; sR[tid] = W2r[tid]; }
    if (tid < 64)  { sS[tid] = 0.f; sT[tid] = 0.f; }

    float acc[4][8];
    #pragma unroll
    for (int i = 0; i < 4; i++)
        #pragma unroll
        for (int j = 0; j < 8; j++) acc[i][j] = 0.f;

    for (int ph = 0; ph < 2; ph++) {
        const float* Wsrc = (ph == 0) ? W1r : W1l;
        const float* Asrc = (ph == 0) ? x : agg;
        __syncthreads();   // previous-phase readers done before restage
        for (int i = tid; i < 128 * 64; i += 256) {
            int o = i >> 6, k = i & 63;
            sW[k * SWS + o] = Wsrc[i];             // transpose to [k][o]
        }
        for (int i = tid; i < 64 * 64; i += 256) {
            int n = i >> 6, k = i & 63;
            int node = node0 + n;
            sXA[n * XAS + k] = (node < N_NODESC) ? Asrc[node * 64 + k] : 0.f;
        }
        __syncthreads();
        #pragma unroll 4
        for (int k = 0; k < 64; k++) {
            const float4* wp = (const float4*)&sW[k * SWS + tx * 8];
            float4 w0 = wp[0];
            float4 w1 = wp[1];
            float a0 = sXA[ty * XAS + k];
            float a1 = sXA[(ty + 16) * XAS + k];
            float a2 = sXA[(ty + 32) * XAS + k];
            float a3 = sXA[(ty + 48) * XAS + k];
            acc[0][0] += a0 * w0.x; acc[0][1] += a0 * w0.y; acc[0][2] += a0 * w0.z; acc[0][3] += a0 * w0.w;
            acc[0][4] += a0 * w1.x; acc[0][5] += a0 * w1.y; acc[0][6] += a0 * w1.z; acc[0][7] += a0 * w1.w;
            acc[1][0] += a1 * w0.x; acc[1][1] += a1 * w0.y; acc[1][2] += a1 * w0.z; acc[1][3] += a1 * w0.w;
            acc[1][4] += a1 * w1.x; acc[1][5] += a1 * w1.y; acc[1][6] += a1 * w1.z; acc[1][7] += a1 * w1.w;
            acc[2][0] += a2 * w0.x; acc[2][1] += a2 * w0.y; acc[2][2] += a2 * w0.z; acc[2][3] += a2 * w0.w;
            acc[2][4] += a2 * w1.x; acc[2][5] += a2 * w1.y; acc[2][6] += a2 * w1.z; acc[2][7] += a2 * w1.w;
            acc[3][0] += a3 * w0.x; acc[3][1] += a3 * w0.y; acc[3][2] += a3 * w0.z; acc[3][3] += a3 * w0.w;
            acc[3][4] += a3 * w1.x; acc[3][5] += a3 * w1.y; acc[3][6] += a3 * w1.z; acc[3][7] += a3 * w1.w;
        }
    }
    // epilogue: bias + relu + per-node dot with w2l/w2r
    #pragma unroll
    for (int ni = 0; ni < 4; ni++) {
        float sp = 0.f, tp = 0.f;
        #pragma unroll
        for (int oj = 0; oj < 8; oj++) {
            int o = tx * 8 + oj;
            float h = acc[ni][oj] + sB[o];
            h = fmaxf(h, 0.f);
            sp += h * sL[o];
            tp += h * sR[o];
        }
        atomicAdd(&sS[ty + 16 * ni], sp);
        atomicAdd(&sT[ty + 16 * ni], tp);
    }
    __syncthreads();
    if (tid < 64) {
        int node = node0 + tid;
        if (node < N_NODESC) { s_out[node] = sS[tid]; t_out[node] = sT[tid]; }
    }
}

// ---------------- K4: layer-2 scalar aggregation + relu -> v ----------------
// 16 lanes per node; edge traffic is 4 B/edge instead of 512 B/edge.
__global__ void k4_layer2(const float* __restrict__ s, const float* __restrict__ t,
                          const int* __restrict__ deg, const int* __restrict__ bucket,
                          const float* __restrict__ b2l, float* __restrict__ v) {
    int tid = threadIdx.x;
    int lane = tid & 15;
    int node = blockIdx.x * 16 + (tid >> 4);
    int d = deg[node];
    int c = min(d, MAXDEG);
    float sum = 0.f;
    for (int k = lane; k < c; k += 16) sum += s[bucket[node * MAXDEG + k]];
    sum += __shfl_xor(sum, 1);
    sum += __shfl_xor(sum, 2);
    sum += __shfl_xor(sum, 4);
    sum += __shfl_xor(sum, 8);
    if (lane == 0) {
        float h = sum / (float)max(d, 1) + b2l[0] + t[node];
        v[node] = fmaxf(h, 0.f);
    }
}

// ---------------- K5: z_partial = fc1_W @ v (bias deferred to K6) -----------
__global__ void k5_fc1(const float* __restrict__ fc1W, const float* __restrict__ v,
                       float* __restrict__ z) {
    int row = blockIdx.x >> 2;
    int part = blockIdx.x & 3;
    const float4* W4 = (const float4*)(fc1W + row * 50000 + part * 12500);
    const float4* v4 = (const float4*)(v + part * 12500);
    float sum = 0.f;
    for (int i = threadIdx.x; i < 3125; i += 256) {
        float4 w = W4[i], a = v4[i];
        sum += w.x * a.x + w.y * a.y + w.z * a.z + w.w * a.w;
    }
    #pragma unroll
    for (int m = 1; m < 64; m <<= 1) sum += __shfl_xor(sum, m);
    __shared__ float red[4];
    if ((threadIdx.x & 63) == 0) red[threadIdx.x >> 6] = sum;
    __syncthreads();
    if (threadIdx.x == 0) atomicAdd(&z[row], red[0] + red[1] + red[2] + red[3]);
}

// ---------------- K6: pred = fc2_W @ (z + fc1_b) + fc2_b --------------------
__global__ void k6_head(const float* __restrict__ z, const float* __restrict__ fc1b,
                        const float* __restrict__ fc2W, const float* __restrict__ fc2b,
                        float* __restrict__ out) {
    int t = threadIdx.x;  // 256 threads
    float val = (z[t] + fc1b[t]) * fc2W[t];
    #pragma unroll
    for (int m = 1; m < 64; m <<= 1) val += __shfl_xor(val, m);
    __shared__ float red[4];
    if ((t & 63) == 0) red[t >> 6] = val;
    __syncthreads();
    if (t == 0) out[0] = red[0] + red[1] + red[2] + red[3] + fc2b[0];
}

extern "C" void kernel_launch(void* const* d_in, const int* in_sizes, int n_in,
                              void* d_out, int out_size, void* d_ws, size_t ws_size,
                              hipStream_t stream) {
    const float* x    = (const float*)d_in[0];
    const int*   ei   = (const int*)d_in[1];   // jax x64 disabled -> int32
    const float* W1l  = (const float*)d_in[2];
    const float* b1l  = (const float*)d_in[3];
    const float* W1r  = (const float*)d_in[4];
    const float* W2l  = (const float*)d_in[5];
    const float* b2l  = (const float*)d_in[6];
    const float* W2r  = (const float*)d_in[7];
    const float* fc1W = (const float*)d_in[8];
    const float* fc1b = (const float*)d_in[9];
    const float* fc2W = (const float*)d_in[10];
    const float* fc2b = (const float*)d_in[11];
    float* out = (float*)d_out;

    // workspace layout (bytes, 512-aligned)
    char* ws = (char*)d_ws;
    int*   deg    = (int*)  (ws + 0);          //   200,000 B
    float* z      = (float*)(ws + 200192);     //     1,024 B
    int*   bucket = (int*)  (ws + 201216);     // 12,800,000 B
    float* agg    = (float*)(ws + 13001216);   // 12,800,000 B
    float* s      = (float*)(ws + 25801216);   //   200,000 B
    float* t      = (float*)(ws + 26001216);   //   200,000 B
    float* v      = (float*)(ws + 26201216);   //   200,000 B  (end 26,401,216)

    k0_init   <<<196,   256, 0, stream>>>(deg, z);
    k1_bucket <<<3125,  256, 0, stream>>>(ei, deg, bucket);
    k2_agg    <<<12500, 256, 0, stream>>>(x, deg, bucket, agg);
    k3_mm_fused<<<782,  256, 0, stream>>>(x, agg, W1l, b1l, W1r, W2l, W2r, s, t);
    k4_layer2 <<<3125,  256, 0, stream>>>(s, t, deg, bucket, b2l, v);
    k5_fc1    <<<1024,  256, 0, stream>>>(fc1W, v, z);
    k6_head   <<<1,     256, 0, stream>>>(z, fc1b, fc2W, fc2b, out);
}

// Round 2
// 239.994 us; speedup vs baseline: 1.0780x; 1.0780x over previous
//
#include <hip/hip_runtime.h>

#define N_NODESC 50000
#define N_EDGESC 800000
#define MAXDEG 64

// ---------------- K0: zero-init deg + z (ws is poisoned 0xAA every call) ----
__global__ void k0_init(int* __restrict__ deg, float* __restrict__ z) {
    int i = blockIdx.x * 256 + threadIdx.x;
    if (i < N_NODESC) deg[i] = 0;
    if (i < 256) z[i] = 0.0f;
}

// ---------------- K1: padded-bucket CSR build (int atomics only) ------------
__global__ void k1_bucket(const int* __restrict__ ei, int* __restrict__ deg,
                          int* __restrict__ bucket) {
    int e = blockIdx.x * 256 + threadIdx.x;
    int src = ei[e];
    int dst = ei[N_EDGESC + e];
    int slot = atomicAdd(&deg[dst], 1);
    if (slot < MAXDEG) bucket[dst * MAXDEG + slot] = src;
}

// ---------------- K2: layer-1 mean aggregation, float4 gathers --------------
// 1 wave/node. lane = (g, c4): g = edge subgroup (4 edges in flight), c4 =
// float4 channel chunk. Each gather instr moves 64 lanes x 16 B = 1 KiB.
__global__ void k2_agg(const float* __restrict__ x, const int* __restrict__ deg,
                       const int* __restrict__ bucket, float* __restrict__ agg) {
    int lane = threadIdx.x & 63;
    int node = blockIdx.x * 4 + (threadIdx.x >> 6);
    int g  = lane >> 4;
    int c4 = lane & 15;
    int d = deg[node];
    int c = min(d, MAXDEG);
    const int* brow = bucket + node * MAXDEG;
    float4 acc = make_float4(0.f, 0.f, 0.f, 0.f);
    int k = 0;
    for (; k + 8 <= c; k += 8) {          // 8 edges/iter: 2 gathers in flight
        int b0 = brow[k + g];
        int b1 = brow[k + 4 + g];
        float4 v0 = ((const float4*)(x + b0 * 64))[c4];
        float4 v1 = ((const float4*)(x + b1 * 64))[c4];
        acc.x += v0.x + v1.x; acc.y += v0.y + v1.y;
        acc.z += v0.z + v1.z; acc.w += v0.w + v1.w;
    }
    for (; k < c; k += 4) {
        if (k + g < c) {
            float4 v = ((const float4*)(x + brow[k + g] * 64))[c4];
            acc.x += v.x; acc.y += v.y; acc.z += v.z; acc.w += v.w;
        }
    }
    // reduce across the 4 edge subgroups (lane bits 4,5)
    #pragma unroll
    for (int m = 16; m <= 32; m <<= 1) {
        acc.x += __shfl_xor(acc.x, m);
        acc.y += __shfl_xor(acc.y, m);
        acc.z += __shfl_xor(acc.z, m);
        acc.w += __shfl_xor(acc.w, m);
    }
    if (g == 0) {
        float inv = 1.0f / (float)max(d, 1);
        float4 r = make_float4(acc.x * inv, acc.y * inv, acc.z * inv, acc.w * inv);
        ((float4*)(agg + node * 64))[c4] = r;
    }
}

// ---------------- K3: fused layer-1 matmul + bias + relu + (s,t) dots -------
// Tile: 64 nodes x 128 outs. NO transpose: sW kept [o][k] (stride 68), sXA
// [n][k] (stride 68). Thread (tx,ty): o = tx+16*oj (8 outs), n = ty+16*ni
// (4 nodes). W-read lanes step 272 B -> 16B-slots tx*16%128: 2 addrs/slot =
// 2-way = free (m136). A-reads: 4-addr broadcast, free. Staging: contiguous
// float4 copy, conflict-free. Epilogue: shfl_xor over tx bits; the
// (wave,ty,ni)->node map partitions 0..63, so plain stores, no atomics.
#define WS 68

__launch_bounds__(256, 3)
__global__ void k3_mm_fused(const float* __restrict__ x, const float* __restrict__ agg,
                            const float* __restrict__ W1l, const float* __restrict__ b1l,
                            const float* __restrict__ W1r,
                            const float* __restrict__ W2l, const float* __restrict__ W2r,
                            float* __restrict__ s_out, float* __restrict__ t_out) {
    __shared__ __align__(16) float sW[128 * WS];   // 34816 B
    __shared__ __align__(16) float sXA[64 * WS];   // 17408 B  (total 52224)

    int tid = threadIdx.x;
    int tx = tid & 15;
    int ty = tid >> 4;
    int node0 = blockIdx.x * 64;

    // epilogue constants in registers (tiny arrays, L2-resident)
    float bR[8], lR[8], rR[8];
    #pragma unroll
    for (int oj = 0; oj < 8; oj++) {
        int o = tx + 16 * oj;
        bR[oj] = b1l[o]; lR[oj] = W2l[o]; rR[oj] = W2r[o];
    }

    float acc[4][8];
    #pragma unroll
    for (int i = 0; i < 4; i++)
        #pragma unroll
        for (int j = 0; j < 8; j++) acc[i][j] = 0.f;

    for (int ph = 0; ph < 2; ph++) {
        const float* Wsrc = (ph == 0) ? W1r : W1l;
        const float* Asrc = (ph == 0) ? x : agg;
        __syncthreads();   // previous-phase readers done before restage
        for (int i = tid * 4; i < 128 * 64; i += 1024) {
            float4 w = *(const float4*)(Wsrc + i);
            int o = i >> 6, k = i & 63;
            *(float4*)&sW[o * WS + k] = w;
        }
        for (int i = tid * 4; i < 64 * 64; i += 1024) {
            int n = i >> 6, k = i & 63;
            int node = node0 + n;
            float4 a = make_float4(0.f, 0.f, 0.f, 0.f);
            if (node < N_NODESC) a = *(const float4*)(Asrc + node * 64 + k);
            *(float4*)&sXA[n * WS + k] = a;
        }
        __syncthreads();
        #pragma unroll 4
        for (int k = 0; k < 64; k += 4) {
            float4 a4[4], w4[8];
            #pragma unroll
            for (int ni = 0; ni < 4; ni++)
                a4[ni] = *(const float4*)&sXA[(ty + 16 * ni) * WS + k];
            #pragma unroll
            for (int oj = 0; oj < 8; oj++)
                w4[oj] = *(const float4*)&sW[(tx + 16 * oj) * WS + k];
            #pragma unroll
            for (int ni = 0; ni < 4; ni++)
                #pragma unroll
                for (int oj = 0; oj < 8; oj++)
                    acc[ni][oj] += a4[ni].x * w4[oj].x + a4[ni].y * w4[oj].y
                                 + a4[ni].z * w4[oj].z + a4[ni].w * w4[oj].w;
        }
    }

    // epilogue: bias + relu + per-node dots with w2l/w2r, reduce over tx
    #pragma unroll
    for (int ni = 0; ni < 4; ni++) {
        float sp = 0.f, tp = 0.f;
        #pragma unroll
        for (int oj = 0; oj < 8; oj++) {
            float h = fmaxf(acc[ni][oj] + bR[oj], 0.f);
            sp += h * lR[oj];
            tp += h * rR[oj];
        }
        #pragma unroll
        for (int m = 1; m <= 8; m <<= 1) {
            sp += __shfl_xor(sp, m);
            tp += __shfl_xor(tp, m);
        }
        if (tx == 0) {
            int node = node0 + ty + 16 * ni;
            if (node < N_NODESC) { s_out[node] = sp; t_out[node] = tp; }
        }
    }
}

// ---------------- K4: layer-2 scalar aggregation + relu -> v ----------------
__global__ void k4_layer2(const float* __restrict__ s, const float* __restrict__ t,
                          const int* __restrict__ deg, const int* __restrict__ bucket,
                          const float* __restrict__ b2l, float* __restrict__ v) {
    int tid = threadIdx.x;
    int lane = tid & 15;
    int node = blockIdx.x * 16 + (tid >> 4);
    int d = deg[node];
    int c = min(d, MAXDEG);
    float sum = 0.f;
    for (int k = lane; k < c; k += 16) sum += s[bucket[node * MAXDEG + k]];
    sum += __shfl_xor(sum, 1);
    sum += __shfl_xor(sum, 2);
    sum += __shfl_xor(sum, 4);
    sum += __shfl_xor(sum, 8);
    if (lane == 0) {
        float h = sum / (float)max(d, 1) + b2l[0] + t[node];
        v[node] = fmaxf(h, 0.f);
    }
}

// ---------------- K5: z_partial = fc1_W @ v (bias deferred to K6) -----------
__global__ void k5_fc1(const float* __restrict__ fc1W, const float* __restrict__ v,
                       float* __restrict__ z) {
    int row = blockIdx.x >> 2;
    int part = blockIdx.x & 3;
    const float4* W4 = (const float4*)(fc1W + row * 50000 + part * 12500);
    const float4* v4 = (const float4*)(v + part * 12500);
    float sum = 0.f;
    for (int i = threadIdx.x; i < 3125; i += 256) {
        float4 w = W4[i], a = v4[i];
        sum += w.x * a.x + w.y * a.y + w.z * a.z + w.w * a.w;
    }
    #pragma unroll
    for (int m = 1; m < 64; m <<= 1) sum += __shfl_xor(sum, m);
    __shared__ float red[4];
    if ((threadIdx.x & 63) == 0) red[threadIdx.x >> 6] = sum;
    __syncthreads();
    if (threadIdx.x == 0) atomicAdd(&z[row], red[0] + red[1] + red[2] + red[3]);
}

// ---------------- K6: pred = fc2_W @ (z + fc1_b) + fc2_b --------------------
__global__ void k6_head(const float* __restrict__ z, const float* __restrict__ fc1b,
                        const float* __restrict__ fc2W, const float* __restrict__ fc2b,
                        float* __restrict__ out) {
    int t = threadIdx.x;  // 256 threads
    float val = (z[t] + fc1b[t]) * fc2W[t];
    #pragma unroll
    for (int m = 1; m < 64; m <<= 1) val += __shfl_xor(val, m);
    __shared__ float red[4];
    if ((t & 63) == 0) red[t >> 6] = val;
    __syncthreads();
    if (t == 0) out[0] = red[0] + red[1] + red[2] + red[3] + fc2b[0];
}

extern "C" void kernel_launch(void* const* d_in, const int* in_sizes, int n_in,
                              void* d_out, int out_size, void* d_ws, size_t ws_size,
                              hipStream_t stream) {
    const float* x    = (const float*)d_in[0];
    const int*   ei   = (const int*)d_in[1];   // jax x64 disabled -> int32
    const float* W1l  = (const float*)d_in[2];
    const float* b1l  = (const float*)d_in[3];
    const float* W1r  = (const float*)d_in[4];
    const float* W2l  = (const float*)d_in[5];
    const float* b2l  = (const float*)d_in[6];
    const float* W2r  = (const float*)d_in[7];
    const float* fc1W = (const float*)d_in[8];
    const float* fc1b = (const float*)d_in[9];
    const float* fc2W = (const float*)d_in[10];
    const float* fc2b = (const float*)d_in[11];
    float* out = (float*)d_out;

    // workspace layout (bytes, 512-aligned)
    char* ws = (char*)d_ws;
    int*   deg    = (int*)  (ws + 0);          //   200,000 B
    float* z      = (float*)(ws + 200192);     //     1,024 B
    int*   bucket = (int*)  (ws + 201216);     // 12,800,000 B
    float* agg    = (float*)(ws + 13001216);   // 12,800,000 B
    float* s      = (float*)(ws + 25801216);   //   200,000 B
    float* t      = (float*)(ws + 26001216);   //   200,000 B
    float* v      = (float*)(ws + 26201216);   //   200,000 B  (end 26,401,216)

    k0_init   <<<196,   256, 0, stream>>>(deg, z);
    k1_bucket <<<3125,  256, 0, stream>>>(ei, deg, bucket);
    k2_agg    <<<12500, 256, 0, stream>>>(x, deg, bucket, agg);
    k3_mm_fused<<<782,  256, 0, stream>>>(x, agg, W1l, b1l, W1r, W2l, W2r, s, t);
    k4_layer2 <<<3125,  256, 0, stream>>>(s, t, deg, bucket, b2l, v);
    k5_fc1    <<<1024,  256, 0, stream>>>(fc1W, v, z);
    k6_head   <<<1,     256, 0, stream>>>(z, fc1b, fc2W, fc2b, out);
}

// Round 3
// 230.271 us; speedup vs baseline: 1.1235x; 1.0422x over previous
//
#include <hip/hip_runtime.h>

#define N_NODESC 50000
#define N_EDGESC 800000
#define MAXDEG 64

// ---------------- K0: zero-init deg + z (ws is poisoned 0xAA every call) ----
__global__ void k0_init(int* __restrict__ deg, float* __restrict__ z) {
    int i = blockIdx.x * 256 + threadIdx.x;
    if (i < N_NODESC) deg[i] = 0;
    if (i < 256) z[i] = 0.0f;
}

// ---------------- K1: XCD-partitioned padded-bucket CSR build ---------------
// 8 dst-range groups; group = blockIdx&7 rides the round-robin block->XCD
// mapping so each group's 1.6 MB bucket slice stays in one XCD's L2: the
// scattered 4B stores merge into full lines before eviction (WRITE_SIZE
// 48 MB -> ~13 MB). Edge list re-read x8 is LIC-hit. Mapping is a locality
// heuristic only -- correctness does not depend on it.
#define K1_BLOCKS 2048
#define K1_EPB (N_EDGESC / (K1_BLOCKS / 8))   // 3125 edges per block
__global__ void k1_bucket(const int* __restrict__ ei, int* __restrict__ deg,
                          int* __restrict__ bucket) {
    int g   = blockIdx.x & 7;
    int idx = blockIdx.x >> 3;
    int lo = g * (N_NODESC / 8), hi = lo + (N_NODESC / 8);
    int e0 = idx * K1_EPB;
    for (int i = threadIdx.x; i < K1_EPB; i += 256) {
        int e = e0 + i;
        int dst = ei[N_EDGESC + e];
        int src = ei[e];
        if (dst >= lo && dst < hi) {
            int slot = atomicAdd(&deg[dst], 1);
            if (slot < MAXDEG) bucket[dst * MAXDEG + slot] = src;
        }
    }
}

// ---------------- K2: layer-1 mean aggregation, float4 gathers --------------
// 1 wave/node. Bucket row prefetched 1 idx/lane, indices distributed via
// shfl -> no dependent index load in the gather chain. lane=(g,c4): g=edge
// subgroup (2 gathers in flight), c4=float4 chunk; 1 KiB per gather instr.
__global__ void k2_agg(const float* __restrict__ x, const int* __restrict__ deg,
                       const int* __restrict__ bucket, float* __restrict__ agg) {
    int lane = threadIdx.x & 63;
    int node = blockIdx.x * 4 + (threadIdx.x >> 6);
    int g  = lane >> 4;
    int c4 = lane & 15;
    int d = deg[node];
    int c = min(d, MAXDEG);
    int bidx = bucket[node * MAXDEG + lane];   // garbage for lane>=c, predicated below
    float4 acc = make_float4(0.f, 0.f, 0.f, 0.f);
    for (int k = 0; k < c; k += 8) {
        int i0 = k + g, i1 = k + 4 + g;
        int b0 = __shfl(bidx, i0);
        int b1 = __shfl(bidx, i1);
        if (i0 < c) {
            float4 v = ((const float4*)(x + b0 * 64))[c4];
            acc.x += v.x; acc.y += v.y; acc.z += v.z; acc.w += v.w;
        }
        if (i1 < c) {
            float4 v = ((const float4*)(x + b1 * 64))[c4];
            acc.x += v.x; acc.y += v.y; acc.z += v.z; acc.w += v.w;
        }
    }
    #pragma unroll
    for (int m = 16; m <= 32; m <<= 1) {
        acc.x += __shfl_xor(acc.x, m);
        acc.y += __shfl_xor(acc.y, m);
        acc.z += __shfl_xor(acc.z, m);
        acc.w += __shfl_xor(acc.w, m);
    }
    if (g == 0) {
        float inv = 1.0f / (float)max(d, 1);
        ((float4*)(agg + node * 64))[c4] =
            make_float4(acc.x * inv, acc.y * inv, acc.z * inv, acc.w * inv);
    }
}

// ---------------- K3: fused layer-1 matmul + bias + relu + (s,t) dots -------
// Tile: 128 nodes x 128 outs, 256 thr, 8x8 microtile: 16 b128 per 4-k for
// 256 FMAs (2x FLOP/LDS-byte vs R2; LDS pipe ~= VALU pipe, balanced).
// Banks: a-reads slot 17n%32 distinct over ty, w-reads 17tx%32 distinct ->
// conflict-free. Epilogue: shfl over tx bits; (wave,ty,ni)->node partitions
// 0..127, plain stores, no atomics. h1 (25.6 MB) never touches HBM.
#define WS 68

__launch_bounds__(256, 2)
__global__ void k3_mm_fused(const float* __restrict__ x, const float* __restrict__ agg,
                            const float* __restrict__ W1l, const float* __restrict__ b1l,
                            const float* __restrict__ W1r,
                            const float* __restrict__ W2l, const float* __restrict__ W2r,
                            float* __restrict__ s_out, float* __restrict__ t_out) {
    __shared__ __align__(16) float sW[128 * WS];    // 34816 B
    __shared__ __align__(16) float sXA[128 * WS];   // 34816 B (69632 -> 2 blk/CU)
    __shared__ float sB[128], sL[128], sR[128];

    int tid = threadIdx.x;
    int tx = tid & 15;
    int ty = tid >> 4;
    int node0 = blockIdx.x * 128;

    if (tid < 128) { sB[tid] = b1l[tid]; sL[tid] = W2l[tid]; sR[tid] = W2r[tid]; }

    float acc[8][8];
    #pragma unroll
    for (int i = 0; i < 8; i++)
        #pragma unroll
        for (int j = 0; j < 8; j++) acc[i][j] = 0.f;

    for (int ph = 0; ph < 2; ph++) {
        const float* Wsrc = (ph == 0) ? W1r : W1l;
        const float* Asrc = (ph == 0) ? x : agg;
        __syncthreads();   // previous-phase readers done before restage
        #pragma unroll
        for (int i = tid * 4; i < 128 * 64; i += 1024) {
            float4 w = *(const float4*)(Wsrc + i);
            int o = i >> 6, k = i & 63;
            *(float4*)&sW[o * WS + k] = w;
        }
        #pragma unroll
        for (int i = tid * 4; i < 128 * 64; i += 1024) {
            int n = i >> 6, k = i & 63;
            int node = node0 + n;
            float4 a = make_float4(0.f, 0.f, 0.f, 0.f);
            if (node < N_NODESC) a = *(const float4*)(Asrc + node * 64 + k);
            *(float4*)&sXA[n * WS + k] = a;
        }
        __syncthreads();
        for (int k = 0; k < 64; k += 4) {
            float4 a4[8], w4[8];
            #pragma unroll
            for (int ni = 0; ni < 8; ni++)
                a4[ni] = *(const float4*)&sXA[(ty + 16 * ni) * WS + k];
            #pragma unroll
            for (int oj = 0; oj < 8; oj++)
                w4[oj] = *(const float4*)&sW[(tx + 16 * oj) * WS + k];
            #pragma unroll
            for (int ni = 0; ni < 8; ni++)
                #pragma unroll
                for (int oj = 0; oj < 8; oj++)
                    acc[ni][oj] += a4[ni].x * w4[oj].x + a4[ni].y * w4[oj].y
                                 + a4[ni].z * w4[oj].z + a4[ni].w * w4[oj].w;
        }
    }

    // epilogue: bias + relu + per-node dots with w2l/w2r, reduce over tx
    #pragma unroll
    for (int ni = 0; ni < 8; ni++) {
        float sp = 0.f, tp = 0.f;
        #pragma unroll
        for (int oj = 0; oj < 8; oj++) {
            int o = tx + 16 * oj;
            float h = fmaxf(acc[ni][oj] + sB[o], 0.f);
            sp += h * sL[o];
            tp += h * sR[o];
        }
        #pragma unroll
        for (int m = 1; m <= 8; m <<= 1) {
            sp += __shfl_xor(sp, m);
            tp += __shfl_xor(tp, m);
        }
        if (tx == 0) {
            int node = node0 + ty + 16 * ni;
            if (node < N_NODESC) { s_out[node] = sp; t_out[node] = tp; }
        }
    }
}

// ---------------- K4: layer-2 scalar aggregation + relu -> v ----------------
__global__ void k4_layer2(const float* __restrict__ s, const float* __restrict__ t,
                          const int* __restrict__ deg, const int* __restrict__ bucket,
                          const float* __restrict__ b2l, float* __restrict__ v) {
    int tid = threadIdx.x;
    int lane = tid & 15;
    int node = blockIdx.x * 16 + (tid >> 4);
    int d = deg[node];
    int c = min(d, MAXDEG);
    float sum = 0.f;
    for (int k = lane; k < c; k += 16) sum += s[bucket[node * MAXDEG + k]];
    sum += __shfl_xor(sum, 1);
    sum += __shfl_xor(sum, 2);
    sum += __shfl_xor(sum, 4);
    sum += __shfl_xor(sum, 8);
    if (lane == 0) {
        float h = sum / (float)max(d, 1) + b2l[0] + t[node];
        v[node] = fmaxf(h, 0.f);
    }
}

// ---------------- K5: z_partial = fc1_W @ v (bias deferred to K6) -----------
__global__ void k5_fc1(const float* __restrict__ fc1W, const float* __restrict__ v,
                       float* __restrict__ z) {
    int row = blockIdx.x >> 2;
    int part = blockIdx.x & 3;
    const float4* W4 = (const float4*)(fc1W + row * 50000 + part * 12500);
    const float4* v4 = (const float4*)(v + part * 12500);
    float sum = 0.f;
    for (int i = threadIdx.x; i < 3125; i += 256) {
        float4 w = W4[i], a = v4[i];
        sum += w.x * a.x + w.y * a.y + w.z * a.z + w.w * a.w;
    }
    #pragma unroll
    for (int m = 1; m < 64; m <<= 1) sum += __shfl_xor(sum, m);
    __shared__ float red[4];
    if ((threadIdx.x & 63) == 0) red[threadIdx.x >> 6] = sum;
    __syncthreads();
    if (threadIdx.x == 0) atomicAdd(&z[row], red[0] + red[1] + red[2] + red[3]);
}

// ---------------- K6: pred = fc2_W @ (z + fc1_b) + fc2_b --------------------
__global__ void k6_head(const float* __restrict__ z, const float* __restrict__ fc1b,
                        const float* __restrict__ fc2W, const float* __restrict__ fc2b,
                        float* __restrict__ out) {
    int t = threadIdx.x;  // 256 threads
    float val = (z[t] + fc1b[t]) * fc2W[t];
    #pragma unroll
    for (int m = 1; m < 64; m <<= 1) val += __shfl_xor(val, m);
    __shared__ float red[4];
    if ((t & 63) == 0) red[t >> 6] = val;
    __syncthreads();
    if (t == 0) out[0] = red[0] + red[1] + red[2] + red[3] + fc2b[0];
}

extern "C" void kernel_launch(void* const* d_in, const int* in_sizes, int n_in,
                              void* d_out, int out_size, void* d_ws, size_t ws_size,
                              hipStream_t stream) {
    const float* x    = (const float*)d_in[0];
    const int*   ei   = (const int*)d_in[1];   // jax x64 disabled -> int32
    const float* W1l  = (const float*)d_in[2];
    const float* b1l  = (const float*)d_in[3];
    const float* W1r  = (const float*)d_in[4];
    const float* W2l  = (const float*)d_in[5];
    const float* b2l  = (const float*)d_in[6];
    const float* W2r  = (const float*)d_in[7];
    const float* fc1W = (const float*)d_in[8];
    const float* fc1b = (const float*)d_in[9];
    const float* fc2W = (const float*)d_in[10];
    const float* fc2b = (const float*)d_in[11];
    float* out = (float*)d_out;

    // workspace layout (bytes, 512-aligned)
    char* ws = (char*)d_ws;
    int*   deg    = (int*)  (ws + 0);          //   200,000 B
    float* z      = (float*)(ws + 200192);     //     1,024 B
    int*   bucket = (int*)  (ws + 201216);     // 12,800,000 B
    float* agg    = (float*)(ws + 13001216);   // 12,800,000 B
    float* s      = (float*)(ws + 25801216);   //   200,000 B
    float* t      = (float*)(ws + 26001216);   //   200,000 B
    float* v      = (float*)(ws + 26201216);   //   200,000 B  (end 26,401,216)

    k0_init   <<<196,   256, 0, stream>>>(deg, z);
    k1_bucket <<<K1_BLOCKS, 256, 0, stream>>>(ei, deg, bucket);
    k2_agg    <<<12500, 256, 0, stream>>>(x, deg, bucket, agg);
    k3_mm_fused<<<391,  256, 0, stream>>>(x, agg, W1l, b1l, W1r, W2l, W2r, s, t);
    k4_layer2 <<<3125,  256, 0, stream>>>(s, t, deg, bucket, b2l, v);
    k5_fc1    <<<1024,  256, 0, stream>>>(fc1W, v, z);
    k6_head   <<<1,     256, 0, stream>>>(z, fc1b, fc2W, fc2b, out);
}

// Round 4
// 214.554 us; speedup vs baseline: 1.2058x; 1.0733x over previous
//
#include <hip/hip_runtime.h>

#define N_NODESC 50000
#define N_EDGESC 800000
#define MAXDEG 64

typedef short bf16x8 __attribute__((ext_vector_type(8)));   // 8 bf16 = 4 VGPRs
typedef float f32x4  __attribute__((ext_vector_type(4)));

__device__ inline unsigned short f2bf(float f) {            // RNE fp32->bf16
    unsigned u = __float_as_uint(f);
    unsigned r = u + 0x7FFFu + ((u >> 16) & 1u);
    return (unsigned short)(r >> 16);
}
__device__ inline float bf2f(unsigned short h) {
    return __uint_as_float(((unsigned)h) << 16);
}

// ---------------- K0: zero-init deg + z (ws is poisoned 0xAA every call) ----
__global__ void k0_init(int* __restrict__ deg, float* __restrict__ z) {
    int i = blockIdx.x * 256 + threadIdx.x;
    if (i < N_NODESC) deg[i] = 0;
    if (i < 256) z[i] = 0.0f;
}

// ---------------- K1: XCD-partitioned padded-bucket CSR build ---------------
// 8 dst-range groups ride the round-robin block->XCD mapping so each group's
// 1.6 MB bucket slice stays L2-local and scattered 4B stores merge into full
// lines. Locality heuristic only -- correctness never depends on placement.
#define K1_BLOCKS 2048
#define K1_EPB (N_EDGESC / (K1_BLOCKS / 8))   // 3125 edges per block
__global__ void k1_bucket(const int* __restrict__ ei, int* __restrict__ deg,
                          int* __restrict__ bucket) {
    int g   = blockIdx.x & 7;
    int idx = blockIdx.x >> 3;
    int lo = g * (N_NODESC / 8), hi = lo + (N_NODESC / 8);
    int e0 = idx * K1_EPB;
    for (int i = threadIdx.x; i < K1_EPB; i += 256) {
        int e = e0 + i;
        int dst = ei[N_EDGESC + e];
        int src = ei[e];
        if (dst >= lo && dst < hi) {
            int slot = atomicAdd(&deg[dst], 1);
            if (slot < MAXDEG) bucket[dst * MAXDEG + slot] = src;
        }
    }
}

// ---------------- K2: layer-1 mean aggregation, float4 gathers --------------
__global__ void k2_agg(const float* __restrict__ x, const int* __restrict__ deg,
                       const int* __restrict__ bucket, float* __restrict__ agg) {
    int lane = threadIdx.x & 63;
    int node = blockIdx.x * 4 + (threadIdx.x >> 6);
    int g  = lane >> 4;
    int c4 = lane & 15;
    int d = deg[node];
    int c = min(d, MAXDEG);
    int bidx = bucket[node * MAXDEG + lane];   // garbage for lane>=c, predicated below
    float4 acc = make_float4(0.f, 0.f, 0.f, 0.f);
    for (int k = 0; k < c; k += 8) {
        int i0 = k + g, i1 = k + 4 + g;
        int b0 = __shfl(bidx, i0);
        int b1 = __shfl(bidx, i1);
        if (i0 < c) {
            float4 v = ((const float4*)(x + b0 * 64))[c4];
            acc.x += v.x; acc.y += v.y; acc.z += v.z; acc.w += v.w;
        }
        if (i1 < c) {
            float4 v = ((const float4*)(x + b1 * 64))[c4];
            acc.x += v.x; acc.y += v.y; acc.z += v.z; acc.w += v.w;
        }
    }
    #pragma unroll
    for (int m = 16; m <= 32; m <<= 1) {
        acc.x += __shfl_xor(acc.x, m);
        acc.y += __shfl_xor(acc.y, m);
        acc.z += __shfl_xor(acc.z, m);
        acc.w += __shfl_xor(acc.w, m);
    }
    if (g == 0) {
        float inv = 1.0f / (float)max(d, 1);
        ((float4*)(agg + node * 64))[c4] =
            make_float4(acc.x * inv, acc.y * inv, acc.z * inv, acc.w * inv);
    }
}

// ---------------- K3: layer-1 via 3-term bf16 MFMA + fused (s,t) epilogue ---
// pre = [x|agg] @ [W1r|W1l].T + b; h1 = relu(pre); s = h1.w2l, t = h1.w2r.
// Split precision: M = A_hi.B_hi + A_lo.B_hi + A_hi.B_lo (bf16 hi/lo, RNE);
// dropped lo.lo term ~2^-18 rel -> ~2e-5 on output, threshold 2.4e-3.
// Block = 64 nodes; wave w owns outs [32w,32w+32) -> B frags in 64 VGPRs,
// loaded once. A staged in LDS bf16 hi/lo, row stride 144 (=18 granules:
// frag reads hit each bank granule exactly 2x = free, m136).
// 16x16x32 layouts (m89/m120): A[m=lane&15][k=quad*8+j],
// B[k=quad*8+j][n=lane&15], D[m=quad*4+reg][n=lane&15].
#define K3S 144   // LDS row stride in bf16 elems (128 + 16 pad)

__launch_bounds__(256, 3)
__global__ void k3_mm_mfma(const float* __restrict__ x, const float* __restrict__ agg,
                           const float* __restrict__ W1l, const float* __restrict__ b1l,
                           const float* __restrict__ W1r,
                           const float* __restrict__ W2l, const float* __restrict__ W2r,
                           float* __restrict__ s_out, float* __restrict__ t_out) {
    __shared__ __align__(16) short sAhi[64 * K3S];   // 18432 B
    __shared__ __align__(16) short sAlo[64 * K3S];   // 18432 B
    __shared__ float sS[64], sT[64];

    int tid = threadIdx.x;
    int lane = tid & 63;
    int wave = tid >> 6;
    int col = lane & 15;
    int quad = lane >> 4;
    int node0 = blockIdx.x * 64;

    if (tid < 64) { sS[tid] = 0.f; sT[tid] = 0.f; }

    // ---- B fragments (wave's 32-out strip) + epilogue constants ----
    int o_base = wave * 32;
    bf16x8 bhi[2][4], blo[2][4];
    float bias_r[2], w2l_r[2], w2r_r[2];
    #pragma unroll
    for (int oc = 0; oc < 2; oc++) {
        int o = o_base + oc * 16 + col;
        bias_r[oc] = b1l[o]; w2l_r[oc] = W2l[o]; w2r_r[oc] = W2r[o];
        #pragma unroll
        for (int ks = 0; ks < 4; ks++) {
            int k0 = ks * 32 + quad * 8;
            const float* wrow = (k0 < 64) ? (W1r + o * 64 + k0)
                                          : (W1l + o * 64 + (k0 - 64));
            #pragma unroll
            for (int j = 0; j < 8; j++) {
                float w = wrow[j];
                unsigned short h = f2bf(w);
                bhi[oc][ks][j] = (short)h;
                blo[oc][ks][j] = (short)f2bf(w - bf2f(h));
            }
        }
    }

    // ---- stage A = [x|agg] as bf16 hi/lo into LDS (coalesced float4 reads) --
    #pragma unroll
    for (int i = 0; i < 4; i++) {
        int c = tid + 256 * i;            // 1024 chunks of 8 elems
        int n = c >> 4, kc = c & 15;
        int node = node0 + n;
        float v[8];
        if (node < N_NODESC) {
            const float* src = (kc < 8) ? (x + node * 64 + kc * 8)
                                        : (agg + node * 64 + (kc - 8) * 8);
            float4 v0 = *(const float4*)src;
            float4 v1 = *(const float4*)(src + 4);
            v[0] = v0.x; v[1] = v0.y; v[2] = v0.z; v[3] = v0.w;
            v[4] = v1.x; v[5] = v1.y; v[6] = v1.z; v[7] = v1.w;
        } else {
            #pragma unroll
            for (int j = 0; j < 8; j++) v[j] = 0.f;
        }
        bf16x8 hv, lv;
        #pragma unroll
        for (int j = 0; j < 8; j++) {
            unsigned short h = f2bf(v[j]);
            hv[j] = (short)h;
            lv[j] = (short)f2bf(v[j] - bf2f(h));
        }
        *(bf16x8*)&sAhi[n * K3S + kc * 8] = hv;
        *(bf16x8*)&sAlo[n * K3S + kc * 8] = lv;
    }
    __syncthreads();

    // ---- main loop: 4 ksteps x 4 node-tiles x 2 out-tiles x 3 terms --------
    f32x4 acc[4][2];
    #pragma unroll
    for (int nt = 0; nt < 4; nt++)
        #pragma unroll
        for (int oc = 0; oc < 2; oc++) acc[nt][oc] = (f32x4)0.f;

    #pragma unroll
    for (int ks = 0; ks < 4; ks++) {
        #pragma unroll
        for (int nt = 0; nt < 4; nt++) {
            int off = (nt * 16 + col) * K3S + ks * 32 + quad * 8;
            bf16x8 ah = *(const bf16x8*)&sAhi[off];
            bf16x8 al = *(const bf16x8*)&sAlo[off];
            #pragma unroll
            for (int oc = 0; oc < 2; oc++) {
                acc[nt][oc] = __builtin_amdgcn_mfma_f32_16x16x32_bf16(ah, bhi[oc][ks], acc[nt][oc], 0, 0, 0);
                acc[nt][oc] = __builtin_amdgcn_mfma_f32_16x16x32_bf16(al, bhi[oc][ks], acc[nt][oc], 0, 0, 0);
                acc[nt][oc] = __builtin_amdgcn_mfma_f32_16x16x32_bf16(ah, blo[oc][ks], acc[nt][oc], 0, 0, 0);
            }
        }
    }

    // ---- epilogue: bias+relu+dots; reduce over out dim (col lanes + waves) --
    #pragma unroll
    for (int nt = 0; nt < 4; nt++) {
        float sp[4] = {0.f, 0.f, 0.f, 0.f};
        float tp[4] = {0.f, 0.f, 0.f, 0.f};
        #pragma unroll
        for (int oc = 0; oc < 2; oc++)
            #pragma unroll
            for (int reg = 0; reg < 4; reg++) {
                float h = fmaxf(acc[nt][oc][reg] + bias_r[oc], 0.f);
                sp[reg] += h * w2l_r[oc];
                tp[reg] += h * w2r_r[oc];
            }
        #pragma unroll
        for (int reg = 0; reg < 4; reg++) {
            #pragma unroll
            for (int m = 1; m <= 8; m <<= 1) {
                sp[reg] += __shfl_xor(sp[reg], m);
                tp[reg] += __shfl_xor(tp[reg], m);
            }
        }
        if (col == 0) {
            int nn = nt * 16 + quad * 4;
            #pragma unroll
            for (int reg = 0; reg < 4; reg++) {
                atomicAdd(&sS[nn + reg], sp[reg]);
                atomicAdd(&sT[nn + reg], tp[reg]);
            }
        }
    }
    __syncthreads();
    if (tid < 64) {
        int node = node0 + tid;
        if (node < N_NODESC) { s_out[node] = sS[tid]; t_out[node] = sT[tid]; }
    }
}

// ---------------- K4: layer-2 scalar aggregation + relu -> v ----------------
__global__ void k4_layer2(const float* __restrict__ s, const float* __restrict__ t,
                          const int* __restrict__ deg, const int* __restrict__ bucket,
                          const float* __restrict__ b2l, float* __restrict__ v) {
    int tid = threadIdx.x;
    int lane = tid & 15;
    int node = blockIdx.x * 16 + (tid >> 4);
    int d = deg[node];
    int c = min(d, MAXDEG);
    float sum = 0.f;
    for (int k = lane; k < c; k += 16) sum += s[bucket[node * MAXDEG + k]];
    sum += __shfl_xor(sum, 1);
    sum += __shfl_xor(sum, 2);
    sum += __shfl_xor(sum, 4);
    sum += __shfl_xor(sum, 8);
    if (lane == 0) {
        float h = sum / (float)max(d, 1) + b2l[0] + t[node];
        v[node] = fmaxf(h, 0.f);
    }
}

// ---------------- K5: z_partial = fc1_W @ v (bias deferred to K6) -----------
__global__ void k5_fc1(const float* __restrict__ fc1W, const float* __restrict__ v,
                       float* __restrict__ z) {
    int row = blockIdx.x >> 2;
    int part = blockIdx.x & 3;
    const float4* W4 = (const float4*)(fc1W + row * 50000 + part * 12500);
    const float4* v4 = (const float4*)(v + part * 12500);
    float sum = 0.f;
    for (int i = threadIdx.x; i < 3125; i += 256) {
        float4 w = W4[i], a = v4[i];
        sum += w.x * a.x + w.y * a.y + w.z * a.z + w.w * a.w;
    }
    #pragma unroll
    for (int m = 1; m < 64; m <<= 1) sum += __shfl_xor(sum, m);
    __shared__ float red[4];
    if ((threadIdx.x & 63) == 0) red[threadIdx.x >> 6] = sum;
    __syncthreads();
    if (threadIdx.x == 0) atomicAdd(&z[row], red[0] + red[1] + red[2] + red[3]);
}

// ---------------- K6: pred = fc2_W @ (z + fc1_b) + fc2_b --------------------
__global__ void k6_head(const float* __restrict__ z, const float* __restrict__ fc1b,
                        const float* __restrict__ fc2W, const float* __restrict__ fc2b,
                        float* __restrict__ out) {
    int t = threadIdx.x;  // 256 threads
    float val = (z[t] + fc1b[t]) * fc2W[t];
    #pragma unroll
    for (int m = 1; m < 64; m <<= 1) val += __shfl_xor(val, m);
    __shared__ float red[4];
    if ((t & 63) == 0) red[t >> 6] = val;
    __syncthreads();
    if (t == 0) out[0] = red[0] + red[1] + red[2] + red[3] + fc2b[0];
}

extern "C" void kernel_launch(void* const* d_in, const int* in_sizes, int n_in,
                              void* d_out, int out_size, void* d_ws, size_t ws_size,
                              hipStream_t stream) {
    const float* x    = (const float*)d_in[0];
    const int*   ei   = (const int*)d_in[1];   // jax x64 disabled -> int32
    const float* W1l  = (const float*)d_in[2];
    const float* b1l  = (const float*)d_in[3];
    const float* W1r  = (const float*)d_in[4];
    const float* W2l  = (const float*)d_in[5];
    const float* b2l  = (const float*)d_in[6];
    const float* W2r  = (const float*)d_in[7];
    const float* fc1W = (const float*)d_in[8];
    const float* fc1b = (const float*)d_in[9];
    const float* fc2W = (const float*)d_in[10];
    const float* fc2b = (const float*)d_in[11];
    float* out = (float*)d_out;

    // workspace layout (bytes, 512-aligned)
    char* ws = (char*)d_ws;
    int*   deg    = (int*)  (ws + 0);          //   200,000 B
    float* z      = (float*)(ws + 200192);     //     1,024 B
    int*   bucket = (int*)  (ws + 201216);     // 12,800,000 B
    float* agg    = (float*)(ws + 13001216);   // 12,800,000 B
    float* s      = (float*)(ws + 25801216);   //   200,000 B
    float* t      = (float*)(ws + 26001216);   //   200,000 B
    float* v      = (float*)(ws + 26201216);   //   200,000 B  (end 26,401,216)

    k0_init   <<<196,   256, 0, stream>>>(deg, z);
    k1_bucket <<<K1_BLOCKS, 256, 0, stream>>>(ei, deg, bucket);
    k2_agg    <<<12500, 256, 0, stream>>>(x, deg, bucket, agg);
    k3_mm_mfma<<<782,  256, 0, stream>>>(x, agg, W1l, b1l, W1r, W2l, W2r, s, t);
    k4_layer2 <<<3125,  256, 0, stream>>>(s, t, deg, bucket, b2l, v);
    k5_fc1    <<<1024,  256, 0, stream>>>(fc1W, v, z);
    k6_head   <<<1,     256, 0, stream>>>(z, fc1b, fc2W, fc2b, out);
}